// Round 12
// baseline (400.153 us; speedup 1.0000x reference)
//
#include <hip/hip_runtime.h>
#include <hip/hip_bf16.h>
#include <math.h>

#define N_NODES 10000
#define N_EDGES 640000
#define C 128
#define BF 16

__device__ __forceinline__ float2 bf2_to_f2(unsigned u) {
    union { unsigned x; float f; } lo, hi;
    lo.x = (u & 0xffffu) << 16;
    hi.x = u & 0xffff0000u;
    float2 r; r.x = lo.f; r.y = hi.f; return r;
}

// tanh-approx GELU, exp2 domain; |err vs exact| <= ~4e-4, branchless.
__device__ __forceinline__ float fast_gelu(float z) {
    float z2 = z * z;
    float p  = z * fmaf(0.044715f, z2, 1.0f);
    float e  = __builtin_amdgcn_exp2f(-2.3022082f * p);
    float r  = __builtin_amdgcn_rcpf(1.0f + e);
    return z * r;
}

__device__ __forceinline__ float2 fma2(float a, float2 b, float2 c) {
    float2 r; r.x = fmaf(a, b.x, c.x); r.y = fmaf(a, b.y, c.y); return r;
}

// --- K1: fused x->bf16 convert (blocks 0..1249) + degree atomics (rest) ---
__global__ __launch_bounds__(256) void k_pre(
    const float* __restrict__ x, __hip_bfloat16* __restrict__ xb,
    const int* __restrict__ ei, int* __restrict__ dr, int* __restrict__ dc)
{
    int b = blockIdx.x;
    if (b < 1250) {
        int i = (b * 256 + threadIdx.x) * 4;
        float4 v = *(const float4*)(x + i);
        xb[i + 0] = __float2bfloat16(v.x);
        xb[i + 1] = __float2bfloat16(v.y);
        xb[i + 2] = __float2bfloat16(v.z);
        xb[i + 3] = __float2bfloat16(v.w);
    } else {
        int e = (b - 1250) * 256 + threadIdx.x;   // 2500 blocks cover N_EDGES
        atomicAdd(&dr[ei[e]], 1);
        atomicAdd(&dc[ei[N_EDGES + e]], 1);
    }
}

// --- K2: exclusive scan of dc -> off, plus inv-sqrt degrees ---
__global__ __launch_bounds__(1024) void k_scan(
    const int* __restrict__ dr, const int* __restrict__ dc,
    int* __restrict__ off, float* __restrict__ ir, float* __restrict__ ic)
{
    __shared__ int shp[1024];
    int t = threadIdx.x;
    int base = t * 10;
    int loc[10];
    int s = 0;
#pragma unroll
    for (int j = 0; j < 10; j++) {
        int i = base + j;
        int v = (i < N_NODES) ? dc[i] : 0;
        loc[j] = s;
        s += v;
    }
    shp[t] = s;
    __syncthreads();
    for (int st = 1; st < 1024; st <<= 1) {
        int a = (t >= st) ? shp[t - st] : 0;
        __syncthreads();
        shp[t] += a;
        __syncthreads();
    }
    int excl = shp[t] - s;
#pragma unroll
    for (int j = 0; j < 10; j++) {
        int i = base + j;
        if (i < N_NODES) {
            off[i] = excl + loc[j];
            ir[i] = rsqrtf((float)(dr[i] + 1));
            ic[i] = rsqrtf((float)(dc[i] + 1));
        }
    }
    if (t == 1023) off[N_NODES] = shp[1023];
}

// --- K3: scatter edge ids into destination buckets (bucket is L2-resident) ---
__global__ void k_scatter(const int* __restrict__ ei, const int* __restrict__ off,
                          int* __restrict__ cur, int* __restrict__ bucket) {
    int e = blockIdx.x * blockDim.x + threadIdx.x;
    if (e < N_EDGES) {
        int c = ei[N_EDGES + e];
        int pos = atomicAdd(&cur[c], 1);
        bucket[off[c] + pos] = e;
    }
}

// --- K4: one wave per node (exclusive ownership -> no atomics, deterministic
//     mapping). 2 channels/lane; payload gathered by edge id (wave-uniform ->
//     broadcast) with 1-ahead pipeline; fused self-loop + GEMV epilogue. ---
__global__ __launch_bounds__(256) void k_nodeagg(
    const int* __restrict__ bucket,
    const int* __restrict__ ei, const float* __restrict__ ew,
    const float* __restrict__ ea,
    const __hip_bfloat16* __restrict__ xb,
    const float* __restrict__ Wb, const float* __restrict__ bb,
    const float* __restrict__ ir, const float* __restrict__ ic,
    const int* __restrict__ off,
    const float* __restrict__ Wl, const float* __restrict__ bl,
    float* __restrict__ out)
{
    int w = threadIdx.x >> 6;                     // wave 0..3
    int n = blockIdx.x * 4 + w;                   // grid = 2500 -> nodes 0..9999
    int lane = threadIdx.x & 63;
    int c0 = lane * 2;

    // W_bond columns for channels c0, c0+1
    float2 wbv[BF];
#pragma unroll
    for (int k = 0; k < BF; k++) wbv[k] = *(const float2*)(Wb + (size_t)k * C + c0);
    float2 bbv = *(const float2*)(bb + c0);

    float icn = ic[n];
    int i0 = off[n], i1 = off[n + 1];

    float2 a = make_float2(0.f, 0.f);
    if (i0 < i1) {
        // 1-ahead payload pipeline (all addresses wave-uniform except xb lane col)
        int eN = __builtin_amdgcn_readfirstlane(bucket[i0]);
        int rN = __builtin_amdgcn_readfirstlane(ei[eN]);
        float wN = ew[eN];
        const float4* eaN = (const float4*)(ea + (size_t)eN * BF);
        float4 qN0 = eaN[0], qN1 = eaN[1], qN2 = eaN[2], qN3 = eaN[3];
        unsigned xN = *((const unsigned*)(xb + (size_t)rN * C) + lane);

        for (int i = i0; i < i1; i++) {
            int r = rN; float wv = wN;
            float4 q0 = qN0, q1 = qN1, q2 = qN2, q3 = qN3;
            unsigned xu = xN;

            if (i + 1 < i1) {                     // prefetch next slot's payload
                int e2 = __builtin_amdgcn_readfirstlane(bucket[i + 1]);
                rN = __builtin_amdgcn_readfirstlane(ei[e2]);
                wN = ew[e2];
                const float4* ep = (const float4*)(ea + (size_t)e2 * BF);
                qN0 = ep[0]; qN1 = ep[1]; qN2 = ep[2]; qN3 = ep[3];
                xN = *((const unsigned*)(xb + (size_t)rN * C) + lane);
            }

            float sc = ir[r] * icn * wv;
            float2 emb = bbv;
            emb = fma2(q0.x, wbv[0],  emb); emb = fma2(q0.y, wbv[1],  emb);
            emb = fma2(q0.z, wbv[2],  emb); emb = fma2(q0.w, wbv[3],  emb);
            emb = fma2(q1.x, wbv[4],  emb); emb = fma2(q1.y, wbv[5],  emb);
            emb = fma2(q1.z, wbv[6],  emb); emb = fma2(q1.w, wbv[7],  emb);
            emb = fma2(q2.x, wbv[8],  emb); emb = fma2(q2.y, wbv[9],  emb);
            emb = fma2(q2.z, wbv[10], emb); emb = fma2(q2.w, wbv[11], emb);
            emb = fma2(q3.x, wbv[12], emb); emb = fma2(q3.y, wbv[13], emb);
            emb = fma2(q3.z, wbv[14], emb); emb = fma2(q3.w, wbv[15], emb);

            float2 xf = bf2_to_f2(xu);
            a.x += fast_gelu(xf.x + emb.x) * sc;
            a.y += fast_gelu(xf.y + emb.y) * sc;
        }
    }

    // self-loop + stage the node's 128-vector in this wave's LDS slice
    __shared__ float shs[4][C];
    {
        float sl = ir[n] * icn;
        float2 xf = bf2_to_f2(*((const unsigned*)(xb + (size_t)n * C) + lane));
        shs[w][c0]     = a.x + fast_gelu(xf.x) * sl;
        shs[w][c0 + 1] = a.y + fast_gelu(xf.y) * sl;
    }
    __syncthreads();   // block-wide for safety (cross-lane LDS RAW)

    // fused GEMV: out[n] = vec @ W_lin + b_lin; 2 output channels/lane
    float2 o = *(const float2*)(bl + c0);
#pragma unroll 8
    for (int k = 0; k < C; k++) {
        float sv = shs[w][k];                     // wave-uniform LDS broadcast
        float2 wlv = *(const float2*)(Wl + (size_t)k * C + c0);   // L2-hot
        o = fma2(sv, wlv, o);
    }
    *(float2*)(out + (size_t)n * C + c0) = o;
}

// ---------------- fallback path (round-5 structure, ws-lean) ----------------
template <bool USEBF>
__global__ __launch_bounds__(512) void k_node_fb(
    const float* __restrict__ x, const __hip_bfloat16* __restrict__ xb,
    const float* __restrict__ ea, const float* __restrict__ ew,
    const float* __restrict__ Wb, const float* __restrict__ bb,
    const int* __restrict__ ei,
    const float* __restrict__ ir, const float* __restrict__ ic,
    const int* __restrict__ off, const int* __restrict__ bucket,
    const float* __restrict__ Wl, const float* __restrict__ bl,
    float* __restrict__ out)
{
    int n = blockIdx.x;
    int t = threadIdx.x & (C - 1);
    int g = threadIdx.x >> 7;
    float icn = ic[n];
    float wb[BF];
#pragma unroll
    for (int k = 0; k < BF; k++) wb[k] = Wb[(size_t)k * C + t];
    float bbt = bb[t];
    float acc = 0.0f;
    if (g == 0) {
        float xv = USEBF ? __bfloat162float(xb[(size_t)n * C + t]) : x[(size_t)n * C + t];
        acc = fast_gelu(xv) * (ir[n] * icn);
    }
    int o0 = off[n], o1 = off[n + 1];
    for (int i = o0 + g; i < o1; i += 4) {
        int e = __builtin_amdgcn_readfirstlane(bucket[i]);
        int r = ei[e];
        float s = ir[r] * icn * ew[e];
        const float4* eapt = (const float4*)(ea + (size_t)e * BF);
        float4 q0 = eapt[0], q1 = eapt[1], q2 = eapt[2], q3 = eapt[3];
        float emb = bbt;
        emb = fmaf(q0.x, wb[0], emb);  emb = fmaf(q0.y, wb[1], emb);
        emb = fmaf(q0.z, wb[2], emb);  emb = fmaf(q0.w, wb[3], emb);
        emb = fmaf(q1.x, wb[4], emb);  emb = fmaf(q1.y, wb[5], emb);
        emb = fmaf(q1.z, wb[6], emb);  emb = fmaf(q1.w, wb[7], emb);
        emb = fmaf(q2.x, wb[8], emb);  emb = fmaf(q2.y, wb[9], emb);
        emb = fmaf(q2.z, wb[10], emb); emb = fmaf(q2.w, wb[11], emb);
        emb = fmaf(q3.x, wb[12], emb); emb = fmaf(q3.y, wb[13], emb);
        emb = fmaf(q3.z, wb[14], emb); emb = fmaf(q3.w, wb[15], emb);
        float xv = USEBF ? __bfloat162float(xb[(size_t)r * C + t]) : x[(size_t)r * C + t];
        acc = fmaf(fast_gelu(xv + emb), s, acc);
    }
    __shared__ float shp[4][C];
    __shared__ float shs[C];
    shp[g][t] = acc;
    __syncthreads();
    if (threadIdx.x < C) {
        int k = threadIdx.x;
        shs[k] = shp[0][k] + shp[1][k] + shp[2][k] + shp[3][k];
    }
    __syncthreads();
    float o = 0.0f;
    int k0 = g * 32;
#pragma unroll 8
    for (int j = 0; j < 32; j++) {
        int k = k0 + j;
        o = fmaf(shs[k], Wl[(size_t)k * C + t], o);
    }
    shp[g][t] = o;
    __syncthreads();
    if (threadIdx.x < C) {
        int c = threadIdx.x;
        out[(size_t)n * C + c] = bl[c] + shp[0][c] + shp[1][c] + shp[2][c] + shp[3][c];
    }
}

__global__ __launch_bounds__(256) void k_cvt_fb(const float* __restrict__ x,
                                                __hip_bfloat16* __restrict__ xb) {
    int i = (blockIdx.x * 256 + threadIdx.x) * 4;
    float4 v = *(const float4*)(x + i);
    xb[i + 0] = __float2bfloat16(v.x);
    xb[i + 1] = __float2bfloat16(v.y);
    xb[i + 2] = __float2bfloat16(v.z);
    xb[i + 3] = __float2bfloat16(v.w);
}

__global__ void k_deg_fb(const int* __restrict__ ei, int* __restrict__ dr, int* __restrict__ dc) {
    int e = blockIdx.x * blockDim.x + threadIdx.x;
    if (e < N_EDGES) {
        atomicAdd(&dr[ei[e]], 1);
        atomicAdd(&dc[ei[N_EDGES + e]], 1);
    }
}

extern "C" void kernel_launch(void* const* d_in, const int* in_sizes, int n_in,
                              void* d_out, int out_size, void* d_ws, size_t ws_size,
                              hipStream_t stream) {
    const float* x  = (const float*)d_in[0];
    const float* ea = (const float*)d_in[1];
    const float* ew = (const float*)d_in[2];
    const float* Wb = (const float*)d_in[3];
    const float* bb = (const float*)d_in[4];
    const float* Wl = (const float*)d_in[5];
    const float* bl = (const float*)d_in[6];
    const int*   ei = (const int*)d_in[7];
    float* out = (float*)d_out;

    // layout (u32 units): xb 640000 | bucket 640000 | off 10304 |
    //   ir 10240 | ic 10240 | dr 10240 | dc 10240 | cur 10240
    const size_t need_new = (size_t)(640000 + 640000 + 10304 + 5 * 10240) * 4;
    const size_t need_bf  = need_new;

    unsigned* w32 = (unsigned*)d_ws;
    if (ws_size >= need_new) {
        __hip_bfloat16* xb = (__hip_bfloat16*)w32;
        int*   bucket = (int*)(w32 + 640000);
        int*   off    = bucket + 640000;
        float* ir     = (float*)(off + 10304);
        float* ic     = ir + 10240;
        int*   dr     = (int*)(ic + 10240);
        int*   dc     = dr + 10240;
        int*   cur    = dc + 10240;

        hipMemsetAsync(dr, 0, 3 * 10240 * sizeof(int), stream);   // dr, dc, cur
        k_pre<<<3750, 256, 0, stream>>>(x, xb, ei, dr, dc);
        k_scan<<<1, 1024, 0, stream>>>(dr, dc, off, ir, ic);
        k_scatter<<<(N_EDGES + 255) / 256, 256, 0, stream>>>(ei, off, cur, bucket);
        k_nodeagg<<<N_NODES / 4, 256, 0, stream>>>(bucket, ei, ew, ea, xb, Wb, bb,
                                                   ir, ic, off, Wl, bl, out);
    } else {
        bool usebf = ws_size >= need_bf;
        __hip_bfloat16* xb = (__hip_bfloat16*)w32;
        int* bucket = (int*)(w32 + (usebf ? 640000 : 0));
        int* off    = bucket + 640000;
        int* dr     = off + 10304;
        int* dc     = dr + 10240;
        int* cur    = dc + 10240;
        float* ir   = (float*)(cur + 10240);
        float* ic   = ir + 10240;

        hipMemsetAsync(dr, 0, 3 * 10240 * sizeof(int), stream);
        if (usebf) k_cvt_fb<<<1250, 256, 0, stream>>>(x, xb);
        k_deg_fb<<<(N_EDGES + 255) / 256, 256, 0, stream>>>(ei, dr, dc);
        k_scan<<<1, 1024, 0, stream>>>(dr, dc, off, ir, ic);
        k_scatter<<<(N_EDGES + 255) / 256, 256, 0, stream>>>(ei, off, cur, bucket);
        if (usebf)
            k_node_fb<true><<<N_NODES, 512, 0, stream>>>(x, xb, ea, ew, Wb, bb, ei, ir, ic, off, bucket, Wl, bl, out);
        else
            k_node_fb<false><<<N_NODES, 512, 0, stream>>>(x, xb, ea, ew, Wb, bb, ei, ir, ic, off, bucket, Wl, bl, out);
    }
}